// Round 2
// baseline (518.242 us; speedup 1.0000x reference)
//
#include <hip/hip_runtime.h>
#include <hip/hip_bf16.h>
#include <stdint.h>

// Problem dims (fixed by the reference)
constexpr int Mdim = 256;    // batch
constexpr int Ndim = 4096;   // codes E
constexpr int Kdim = 16384;  // EMB

// GEMM tiling
constexpr int MT = 128;
constexpr int NT = 128;
constexpr int KS = 16;            // split-K -> grid 32*2*16 = 1024 blocks
constexpr int KC = Kdim / KS;     // 1024
constexpr int BK = 32;            // K per LDS tile
constexpr int NITER = KC / BK;    // 32

typedef __attribute__((ext_vector_type(8))) short short8;  // 8 x bf16 (4 VGPR)
typedef __attribute__((ext_vector_type(4))) float f32x4;

static_assert(Mdim % MT == 0 && Ndim % NT == 0 && Kdim % (KS * BK) == 0, "tiling");

// packed fp32x2 -> bf16x2 RNE (maps to v_cvt_pk_bf16_f32 on gfx950)
__device__ __forceinline__ unsigned int cvt2(float lo, float hi) {
  union { __hip_bfloat162 h; unsigned int u; } v;
  v.h = __float22bfloat162_rn(make_float2(lo, hi));
  return v.u;  // .x in low 16 bits
}

// Single-bf16 MFMA GEMM: dst partial scores = ||e||^2_chunk - 2 * x.e|_chunk
__global__ __launch_bounds__(256) void k_gemm(const float* __restrict__ x,
                                              const float* __restrict__ e,
                                              float* __restrict__ dst,
                                              int ws_mode) {
  // fragment-ordered LDS: [buf][A=0/B=1][k-octet][row][8 bf16] = 32 KiB
  __shared__ short lds[2][2][4][128][8];
  __shared__ float esq_part[256];
  __shared__ float esq_sh[128];

  const int t  = threadIdx.x;
  const int n0 = blockIdx.x * NT;
  const int m0 = blockIdx.y * MT;
  const int kz = blockIdx.z;
  const int k0 = kz * KC;

  // staging: 2 threads per row, 16 contiguous floats each (octets g0, g0+1)
  const int r  = t >> 1;
  const int kq = (t & 1) * 16;
  const int g0 = (t & 1) * 2;
  const float* xp = x + (size_t)(m0 + r) * Kdim + k0 + kq;
  const float* ep = e + (size_t)(n0 + r) * Kdim + k0 + kq;

  // wave -> 64x64 quadrant, 4x4 subtiles of 16x16
  const int wave = t >> 6;
  const int lane = t & 63;
  const int wm   = (wave & 1) * 64;
  const int wn   = (wave >> 1) * 64;
  const int lcol = lane & 15;
  const int quad = lane >> 4;

  f32x4 acc[4][4] = {};
  float esq_acc = 0.0f;

  float4 bufA[4], bufB[4];
#pragma unroll
  for (int g = 0; g < 4; ++g) {
    bufA[g] = ((const float4*)xp)[g];
    bufB[g] = ((const float4*)ep)[g];
  }

  // convert staged regs -> bf16, write LDS buf, accumulate ||e||^2 chunk
  auto stage = [&](int buf) {
    union { short8 s; unsigned int u[4]; } pa0, pa1, pb0, pb1;
    pa0.u[0] = cvt2(bufA[0].x, bufA[0].y); pa0.u[1] = cvt2(bufA[0].z, bufA[0].w);
    pa0.u[2] = cvt2(bufA[1].x, bufA[1].y); pa0.u[3] = cvt2(bufA[1].z, bufA[1].w);
    pa1.u[0] = cvt2(bufA[2].x, bufA[2].y); pa1.u[1] = cvt2(bufA[2].z, bufA[2].w);
    pa1.u[2] = cvt2(bufA[3].x, bufA[3].y); pa1.u[3] = cvt2(bufA[3].z, bufA[3].w);
    pb0.u[0] = cvt2(bufB[0].x, bufB[0].y); pb0.u[1] = cvt2(bufB[0].z, bufB[0].w);
    pb0.u[2] = cvt2(bufB[1].x, bufB[1].y); pb0.u[3] = cvt2(bufB[1].z, bufB[1].w);
    pb1.u[0] = cvt2(bufB[2].x, bufB[2].y); pb1.u[1] = cvt2(bufB[2].z, bufB[2].w);
    pb1.u[2] = cvt2(bufB[3].x, bufB[3].y); pb1.u[3] = cvt2(bufB[3].z, bufB[3].w);
#pragma unroll
    for (int g = 0; g < 4; ++g) {
      esq_acc += bufB[g].x * bufB[g].x + bufB[g].y * bufB[g].y
               + bufB[g].z * bufB[g].z + bufB[g].w * bufB[g].w;
    }
    *(short8*)&lds[buf][0][g0    ][r][0] = pa0.s;
    *(short8*)&lds[buf][0][g0 + 1][r][0] = pa1.s;
    *(short8*)&lds[buf][1][g0    ][r][0] = pb0.s;
    *(short8*)&lds[buf][1][g0 + 1][r][0] = pb1.s;
  };

  stage(0);
  __syncthreads();

  for (int it = 0; it < NITER; ++it) {
    const int cur = it & 1;
    if (it + 1 < NITER) {  // prefetch next tile's globals
      const float* xn = xp + (size_t)(it + 1) * BK;
      const float* en = ep + (size_t)(it + 1) * BK;
#pragma unroll
      for (int g = 0; g < 4; ++g) {
        bufA[g] = ((const float4*)xn)[g];
        bufB[g] = ((const float4*)en)[g];
      }
    }
    // fragments: A[m=lane&15][k=quad*8+j] -> octet = quad, canonical b128 reads
    short8 af[4], bfr[4];
#pragma unroll
    for (int mi = 0; mi < 4; ++mi)
      af[mi] = *(const short8*)&lds[cur][0][quad][wm + mi * 16 + lcol][0];
#pragma unroll
    for (int ni = 0; ni < 4; ++ni)
      bfr[ni] = *(const short8*)&lds[cur][1][quad][wn + ni * 16 + lcol][0];
#pragma unroll
    for (int mi = 0; mi < 4; ++mi)
#pragma unroll
      for (int ni = 0; ni < 4; ++ni)
        acc[mi][ni] = __builtin_amdgcn_mfma_f32_16x16x32_bf16(af[mi], bfr[ni], acc[mi][ni], 0, 0, 0);

    if (it + 1 < NITER) {
      stage(cur ^ 1);     // write other buffer; prior readers fenced by last barrier
      __syncthreads();
    }
  }

  // ||e||^2 chunk: thread t holds partial for code (t>>1)
  esq_part[t] = esq_acc;
  __syncthreads();
  if (t < 128) esq_sh[t] = esq_part[2 * t] + esq_part[2 * t + 1];
  __syncthreads();

  // epilogue: C/D layout col=lane&15, row=quad*4+reg
  if (ws_mode) {
    float* base = dst + (size_t)kz * Mdim * Ndim;
#pragma unroll
    for (int mi = 0; mi < 4; ++mi)
#pragma unroll
      for (int ni = 0; ni < 4; ++ni)
#pragma unroll
        for (int reg = 0; reg < 4; ++reg) {
          int row = m0 + wm + mi * 16 + quad * 4 + reg;
          int cl  = wn + ni * 16 + lcol;
          base[(size_t)row * Ndim + n0 + cl] = esq_sh[cl] - 2.0f * acc[mi][ni][reg];
        }
  } else {
#pragma unroll
    for (int mi = 0; mi < 4; ++mi)
#pragma unroll
      for (int ni = 0; ni < 4; ++ni)
#pragma unroll
        for (int reg = 0; reg < 4; ++reg) {
          int row = m0 + wm + mi * 16 + quad * 4 + reg;
          int cl  = wn + ni * 16 + lcol;
          atomicAdd(&dst[(size_t)row * Ndim + n0 + cl], esq_sh[cl] - 2.0f * acc[mi][ni][reg]);
        }
  }
}

// fused: split-K reduce + top-2 + exact fp32 refine + one-hot write
__global__ __launch_bounds__(256) void k_select(const float* __restrict__ part, int nz,
                                                const float* __restrict__ x,
                                                const float* __restrict__ e,
                                                float* __restrict__ out) {
  __shared__ float sv1[256], sv2[256];
  __shared__ int   si1[256], si2[256];
  __shared__ float s1[256], s2[256];
  __shared__ int win_sh;
  const int b = blockIdx.x, t = threadIdx.x;

  // phase 1: reduce partials over z while tracking per-thread top-2
  float v1 = 3.4e38f, v2 = 3.4e38f; int i1 = 0, i2 = 1;
  for (int c = t; c < Ndim; c += 256) {
    float s = 0.f;
    for (int z = 0; z < nz; ++z) s += part[((size_t)z * Mdim + b) * Ndim + c];
    if (s < v1)      { v2 = v1; i2 = i1; v1 = s; i1 = c; }
    else if (s < v2) { v2 = s;  i2 = c; }
  }
  sv1[t] = v1; si1[t] = i1; sv2[t] = v2; si2[t] = i2;
  __syncthreads();
  for (int sOff = 128; sOff > 0; sOff >>= 1) {
    if (t < sOff) {
      float bv1 = sv1[t + sOff], bv2 = sv2[t + sOff];
      int   bi1 = si1[t + sOff], bi2 = si2[t + sOff];
      float av1 = sv1[t],        av2 = sv2[t];
      int   ai1 = si1[t],        ai2 = si2[t];
      if (bv1 < av1)      { av2 = av1; ai2 = ai1; av1 = bv1; ai1 = bi1; }
      else if (bv1 < av2) { av2 = bv1; ai2 = bi1; }
      if (bv2 < av2)      { av2 = bv2; ai2 = bi2; }
      sv1[t] = av1; si1[t] = ai1; sv2[t] = av2; si2[t] = ai2;
    }
    __syncthreads();
  }
  const int c1 = si1[0], c2 = si2[0];

  // phase 2: exact fp32 distance for the two candidates
  const float4* xb = (const float4*)(x + (size_t)b  * Kdim);
  const float4* e1 = (const float4*)(e + (size_t)c1 * Kdim);
  const float4* e2 = (const float4*)(e + (size_t)c2 * Kdim);
  float a1 = 0.f, a2 = 0.f;
  for (int i = 0; i < Kdim / 4 / 256; ++i) {
    int q = t + i * 256;
    float4 xv  = xb[q];
    float4 ev1 = e1[q];
    float4 ev2 = e2[q];
    a1 += ev1.x * (ev1.x - 2.f * xv.x) + ev1.y * (ev1.y - 2.f * xv.y)
        + ev1.z * (ev1.z - 2.f * xv.z) + ev1.w * (ev1.w - 2.f * xv.w);
    a2 += ev2.x * (ev2.x - 2.f * xv.x) + ev2.y * (ev2.y - 2.f * xv.y)
        + ev2.z * (ev2.z - 2.f * xv.z) + ev2.w * (ev2.w - 2.f * xv.w);
  }
  s1[t] = a1; s2[t] = a2;
  __syncthreads();
  for (int sOff = 128; sOff > 0; sOff >>= 1) {
    if (t < sOff) { s1[t] += s1[t + sOff]; s2[t] += s2[t + sOff]; }
    __syncthreads();
  }
  if (t == 0) {
    float d1 = s1[0], d2 = s2[0];
    win_sh = (d2 < d1 || (d2 == d1 && c2 < c1)) ? c2 : c1;  // np.argmin tie: smaller idx
  }
  __syncthreads();

  // phase 3: one-hot row write (zeroes the 0xAA poison)
  const int win = win_sh;
  float* outb = out + (size_t)b * Ndim;
#pragma unroll
  for (int g = 0; g < 4; ++g) {
    int q = g * 256 + t;
    float4 v;
    v.x = (win == 4 * q + 0) ? 1.f : 0.f;
    v.y = (win == 4 * q + 1) ? 1.f : 0.f;
    v.z = (win == 4 * q + 2) ? 1.f : 0.f;
    v.w = (win == 4 * q + 3) ? 1.f : 0.f;
    ((float4*)outb)[q] = v;
  }
}

extern "C" void kernel_launch(void* const* d_in, const int* in_sizes, int n_in,
                              void* d_out, int out_size, void* d_ws, size_t ws_size,
                              hipStream_t stream) {
  (void)in_sizes; (void)n_in; (void)out_size;
  const float* x = (const float*)d_in[0];  // [256, 16384] fp32
  const float* e = (const float*)d_in[1];  // [4096, 16384] fp32
  float* out = (float*)d_out;

  const size_t part_bytes = (size_t)KS * Mdim * Ndim * sizeof(float);  // 64 MB
  const bool use_ws = ws_size >= part_bytes;
  float* part = use_ws ? (float*)d_ws : out;

  if (!use_ws) {
    // atomic fallback: scores accumulate in d_out, must start at zero
    hipMemsetAsync(d_out, 0, (size_t)Mdim * Ndim * sizeof(float), stream);
  }
  dim3 gG(Ndim / NT, Mdim / MT, KS);
  hipLaunchKernelGGL(k_gemm, gG, dim3(256), 0, stream, x, e, part, (int)use_ws);
  hipLaunchKernelGGL(k_select, dim3(Mdim), dim3(256), 0, stream,
                     part, use_ws ? KS : 1, x, e, out);
}